// Round 2
// baseline (197.039 us; speedup 1.0000x reference)
//
#include <hip/hip_runtime.h>
#include <hip/hip_bf16.h>
#include <stdint.h>

// Problem constants (fixed by reference setup_inputs)
constexpr int E_NUM  = 8;
constexpr int I_DIM  = 1024;
constexpr int O_DIM  = 1024;
constexpr int B_SEG  = 16;
constexpr int N_ROWS = 16384;

// GEMM tiling: 256x256 tile, BK=64, 512 threads = 8 waves (2 M x 4 N)
constexpr int BM = 256, BN = 256, BK = 64;
constexpr int NT = I_DIM / BK;          // 16 K-tiles

typedef __bf16 bf16x8 __attribute__((ext_vector_type(8)));
typedef float  f32x4  __attribute__((ext_vector_type(4)));
typedef unsigned short ushortx8 __attribute__((ext_vector_type(8)));

#define AS1 __attribute__((address_space(1)))
#define AS3 __attribute__((address_space(3)))

__device__ __forceinline__ unsigned short f2bf(float f) {
    unsigned int u = __float_as_uint(f);
    u += 0x7fffu + ((u >> 16) & 1u);
    return (unsigned short)(u >> 16);
}

// ---------------------------------------------------------------------------
// prep: fused cvt_x (blocks 0..4095) + synth_w (blocks 4096..4607).
// Independent memory-bound phases in one launch -> overlap + one less gap.
// ---------------------------------------------------------------------------
__global__ __launch_bounds__(256) void prep(const float* __restrict__ x,
                                            unsigned short* __restrict__ xb,
                                            const float* __restrict__ w,
                                            const float* __restrict__ coeff,
                                            unsigned short* __restrict__ wb) {
    __shared__ float sc[B_SEG * E_NUM];
    const int bid = blockIdx.x;
    const int tid = threadIdx.x;

    if (bid < 4096) {
        // ---- cvt_x part: x fp32 -> bf16, 64B in / 32B out per thread ----
        size_t idx = ((size_t)bid * 256 + tid) * 16;
        const float4* p = (const float4*)(x + idx);
        float4 v0 = p[0], v1 = p[1], v2 = p[2], v3 = p[3];
        ushortx8 o0, o1;
        o0[0] = f2bf(v0.x); o0[1] = f2bf(v0.y); o0[2] = f2bf(v0.z); o0[3] = f2bf(v0.w);
        o0[4] = f2bf(v1.x); o0[5] = f2bf(v1.y); o0[6] = f2bf(v1.z); o0[7] = f2bf(v1.w);
        o1[0] = f2bf(v2.x); o1[1] = f2bf(v2.y); o1[2] = f2bf(v2.z); o1[3] = f2bf(v2.w);
        o1[4] = f2bf(v3.x); o1[5] = f2bf(v3.y); o1[6] = f2bf(v3.z); o1[7] = f2bf(v3.w);
        *(ushortx8*)(xb + idx)     = o0;
        *(ushortx8*)(xb + idx + 8) = o1;
    } else {
        // ---- synth_w part: W_b[o,i] = sum_e coeff[b,e] * weights[e,o,i] ----
        if (tid < B_SEG * E_NUM) sc[tid] = coeff[tid];
        __syncthreads();

        size_t idx = ((size_t)(bid - 4096) * 256 + tid) * 8;   // into [O*I)
        float4 wv0[E_NUM], wv1[E_NUM];
#pragma unroll
        for (int e = 0; e < E_NUM; e++) {
            const float4* p = (const float4*)(w + (size_t)e * O_DIM * I_DIM + idx);
            wv0[e] = p[0];
            wv1[e] = p[1];
        }

#pragma unroll
        for (int b = 0; b < B_SEG; b++) {
            float a[8] = {0,0,0,0,0,0,0,0};
#pragma unroll
            for (int e = 0; e < E_NUM; e++) {
                float c = sc[b * E_NUM + e];
                a[0] += c * wv0[e].x; a[1] += c * wv0[e].y;
                a[2] += c * wv0[e].z; a[3] += c * wv0[e].w;
                a[4] += c * wv1[e].x; a[5] += c * wv1[e].y;
                a[6] += c * wv1[e].z; a[7] += c * wv1[e].w;
            }
            ushortx8 o;
#pragma unroll
            for (int j = 0; j < 8; j++) o[j] = f2bf(a[j]);
            *(ushortx8*)(wb + (size_t)b * O_DIM * I_DIM + idx) = o;
        }
    }
}

// ---------------------------------------------------------------------------
// opaque LDS read (rule 18: manual lgkmcnt + sched_barrier afterwards)
// ---------------------------------------------------------------------------
__device__ __forceinline__ bf16x8 lds_read_b128(unsigned addr) {
    bf16x8 r;
    asm volatile("ds_read_b128 %0, %1" : "=v"(r) : "v"(addr));
    return r;
}

// ---------------------------------------------------------------------------
// Kernel 3: per-segment GEMM, C = X * W_seg^T + bias.
// m201-style 8-phase schedule: 256x256 tile, BK=64, 8 waves (2Mx4N),
// stripe-interleaved wave mapping (wave rows m*32+wr*16, cols n*64+wc*16)
// so each phase's operand half is wave-uniform. Half-tile ring of 4 slots
// per operand (A: bytes 0..64K, B: 64K..128K). Per phase: ds_reads + 1
// half-tile stage + barrier + lgkmcnt(0) + setprio'd 16 MFMA + barrier.
// Counted vmcnt(4) once per K-tile; never drained in the main loop.
// ---------------------------------------------------------------------------
__global__ __launch_bounds__(512, 2) void gemm_moe(
    const unsigned short* __restrict__ xb,   // [N][I] bf16 bits
    const unsigned short* __restrict__ wb,   // [B][O][I] bf16 bits
    const float* __restrict__ bias,          // [O]
    const int* __restrict__ msz,             // [B]
    float* __restrict__ out)                 // [N][O] fp32
{
    __shared__ __align__(16) char sLDS[131072];   // A: 4x16KB, B: 4x16KB

    // ---- XCD-aware mapping: 256 blocks, lid%8 = XCD, 2 segments per XCD,
    // 4x4 tiles of 256^2 per segment.
    const int lid  = blockIdx.x;            // 0..255
    const int xcd  = lid & 7;
    const int idx  = lid >> 3;              // 0..31
    const int seg  = (xcd << 1) | (idx >> 4);
    const int t16  = idx & 15;
    const int mblk = t16 >> 2;
    const int nblk = t16 & 3;

    int off = 0;
    for (int b = 0; b < seg; b++) off += msz[b];
    const int row0 = off + mblk * BM;
    const int col0 = nblk * BN;
    const unsigned short* wseg = wb + (size_t)seg * O_DIM * I_DIM;

    const int tid  = threadIdx.x;
    const int wave = tid >> 6;              // 0..7
    const int lane = tid & 63;
    const int wr = wave >> 2, wc = wave & 3;
    const int quad = lane >> 4, l16 = lane & 15;

    // ---- staging source geometry: 512 threads cover one 128x64 half-tile
    // with 2 global_load_lds (64 rows each). LDS dest linear; K-chunk XOR
    // swizzle (chunk ^= row&7) applied to the per-lane GLOBAL source.
    const int srow8  = lane >> 3;                       // 0..7
    const int schunk = (lane & 7) ^ srow8;              // swizzled K-chunk
    const unsigned short* gA0 = xb   + (size_t)(row0 + wave * 8 + srow8) * I_DIM + schunk * 8;
    const unsigned short* gA1 = gA0 + (size_t)128 * I_DIM;
    const unsigned short* gB0 = wseg + (size_t)(col0 + wave * 8 + srow8) * I_DIM + schunk * 8;
    const unsigned short* gB1 = gB0 + (size_t)128 * I_DIM;

    // ---- ds_read lane addresses (bytes). Row within half: A: (m&3)*32 +
    // wr*16 + l16 ; B: (n&1)*64 + wc*16 + l16. chunk = (kk*4+quad)^(l16&7).
    const unsigned rdA0 = (unsigned)((wr * 16 + l16) * 128 + (((0 + quad) ^ (l16 & 7)) * 16));
    const unsigned rdA1 = (unsigned)((wr * 16 + l16) * 128 + (((4 + quad) ^ (l16 & 7)) * 16));
    const unsigned rdB0 = (unsigned)(65536 + (wc * 16 + l16) * 128 + (((0 + quad) ^ (l16 & 7)) * 16));
    const unsigned rdB1 = (unsigned)(65536 + (wc * 16 + l16) * 128 + (((4 + quad) ^ (l16 & 7)) * 16));

    bf16x8 af[4][2], bfr[2][2];
    f32x4 acc[8][4];
#pragma unroll
    for (int m = 0; m < 8; ++m)
#pragma unroll
        for (int n = 0; n < 4; ++n)
            acc[m][n] = (f32x4){0.f, 0.f, 0.f, 0.f};

#define LOAD_A(S) do { _Pragma("unroll") for (int mm = 0; mm < 4; ++mm) {           \
        af[mm][0] = lds_read_b128(rdA0 + (S) * 16384u + mm * 4096u);                \
        af[mm][1] = lds_read_b128(rdA1 + (S) * 16384u + mm * 4096u); } } while (0)
#define LOAD_B(S) do { _Pragma("unroll") for (int nn = 0; nn < 2; ++nn) {           \
        bfr[nn][0] = lds_read_b128(rdB0 + (S) * 16384u + nn * 8192u);               \
        bfr[nn][1] = lds_read_b128(rdB1 + (S) * 16384u + nn * 8192u); } } while (0)

#define STAGE_A(H, S, ST) do {                                                      \
        const unsigned short* g_ = ((H) ? gA1 : gA0) + (size_t)(ST) * 64;           \
        __builtin_amdgcn_global_load_lds((const AS1 void*)g_,                       \
            (AS3 void*)(sLDS + (S) * 16384 + wave * 1024), 16, 0, 0);               \
        __builtin_amdgcn_global_load_lds((const AS1 void*)(g_ + (size_t)64 * I_DIM),\
            (AS3 void*)(sLDS + (S) * 16384 + 8192 + wave * 1024), 16, 0, 0); } while (0)
#define STAGE_B(H, S, ST) do {                                                      \
        const unsigned short* g_ = ((H) ? gB1 : gB0) + (size_t)(ST) * 64;           \
        __builtin_amdgcn_global_load_lds((const AS1 void*)g_,                       \
            (AS3 void*)(sLDS + 65536 + (S) * 16384 + wave * 1024), 16, 0, 0);       \
        __builtin_amdgcn_global_load_lds((const AS1 void*)(g_ + (size_t)64 * I_DIM),\
            (AS3 void*)(sLDS + 65536 + (S) * 16384 + 8192 + wave * 1024), 16, 0, 0); } while (0)

#define MFMA_Q(MH, NH) do { _Pragma("unroll") for (int mm = 0; mm < 4; ++mm)        \
        _Pragma("unroll") for (int nn = 0; nn < 2; ++nn)                            \
        _Pragma("unroll") for (int kk = 0; kk < 2; ++kk)                            \
            acc[(MH) * 4 + mm][(NH) * 2 + nn] =                                     \
                __builtin_amdgcn_mfma_f32_16x16x32_bf16(af[mm][kk], bfr[nn][kk],    \
                    acc[(MH) * 4 + mm][(NH) * 2 + nn], 0, 0, 0); } while (0)

#define PH_MID() do { __builtin_amdgcn_s_barrier();                                 \
        asm volatile("s_waitcnt lgkmcnt(0)");                                       \
        __builtin_amdgcn_sched_barrier(0);                                          \
        __builtin_amdgcn_s_setprio(1); } while (0)
#define PH_END() do { __builtin_amdgcn_s_setprio(0);                                \
        __builtin_amdgcn_sched_barrier(0);                                          \
        __builtin_amdgcn_s_barrier(); } while (0)

    // TILE: reads A/B halves from slots RS0 (h0), RS1 (h1); stages tile t+1's
    // h1 halves into SS01 (q0,q1) and tile t+2's h0 halves into SS23 (q2,q3).
    // Ring algebra: every staged slot's last reader finished >=1 phase earlier.
#define TILE(RS0, RS1, SS01, SS23, ST1, ST2) do {                                   \
        /* q0: mh0 x nh1 */                                                         \
        LOAD_A(RS0); LOAD_B(RS1); STAGE_A(1, SS01, ST1);                            \
        PH_MID(); MFMA_Q(0, 1); PH_END();                                           \
        /* q1: mh0 x nh0 */                                                         \
        LOAD_B(RS0); STAGE_B(1, SS01, ST1);                                         \
        PH_MID(); MFMA_Q(0, 0); PH_END();                                           \
        /* q2: mh1 x nh0 (B regs reused) */                                         \
        LOAD_A(RS1); STAGE_A(0, SS23, ST2);                                         \
        PH_MID(); MFMA_Q(1, 0); PH_END();                                           \
        /* q3: mh1 x nh1 */                                                         \
        LOAD_B(RS1); STAGE_B(0, SS23, ST2);                                         \
        PH_MID(); MFMA_Q(1, 1);                                                     \
        __builtin_amdgcn_s_setprio(0);                                              \
        __builtin_amdgcn_sched_barrier(0);                                          \
        asm volatile("s_waitcnt vmcnt(4)");                                         \
        __builtin_amdgcn_sched_barrier(0);                                          \
        __builtin_amdgcn_s_barrier();                                               \
    } while (0)

    // ---- prologue: halves s0..s5 = tile0 {Ah0,Bh0,Ah1,Bh1} -> slots 0,0,1,1;
    // tile1 {Ah0,Bh0} -> slot 2. vmcnt(4): s0..s3 landed, s4/s5 in flight.
    STAGE_A(0, 0, 0); STAGE_B(0, 0, 0);
    STAGE_A(1, 1, 0); STAGE_B(1, 1, 0);
    STAGE_A(0, 2, 1); STAGE_B(0, 2, 1);
    asm volatile("s_waitcnt vmcnt(4)");
    __builtin_amdgcn_sched_barrier(0);
    __builtin_amdgcn_s_barrier();

#pragma unroll 1
    for (int tp = 0; tp < 8; ++tp) {
        const int t0 = 2 * tp, t1 = t0 + 1;
        const int s1a = (t0 + 1 < 15) ? t0 + 1 : 15;   // clamped tail sources
        const int s2a = (t0 + 2 < 15) ? t0 + 2 : 15;   // keep vmcnt credits uniform
        const int s1b = (t1 + 1 < 15) ? t1 + 1 : 15;
        const int s2b = (t1 + 2 < 15) ? t1 + 2 : 15;
        // even tile: read A/B slots 0,1; stage -> slots 3 (t+1 h1), 0 (t+2 h0)
        TILE(0, 1, 3, 0, s1a, s2a);
        // odd tile: read slots 2,3; stage -> slots 1, 2
        TILE(2, 3, 1, 2, s1b, s2b);
    }

#undef TILE
#undef PH_END
#undef PH_MID
#undef MFMA_Q
#undef STAGE_B
#undef STAGE_A
#undef LOAD_B
#undef LOAD_A

    // ---- epilogue: C/D layout col=lane&15, row=quad*4+reg; stripe mapping:
    // row = row0 + m*32 + wr*16 + ..., col = col0 + n*64 + wc*16 + l16.
    float bv[4];
#pragma unroll
    for (int n = 0; n < 4; ++n)
        bv[n] = bias[col0 + n * 64 + wc * 16 + l16];

#pragma unroll
    for (int m = 0; m < 8; ++m) {
#pragma unroll
        for (int r = 0; r < 4; ++r) {
            int row = row0 + m * 32 + wr * 16 + quad * 4 + r;
            float* po = out + (size_t)row * O_DIM + col0 + wc * 16 + l16;
#pragma unroll
            for (int n = 0; n < 4; ++n)
                po[n * 64] = acc[m][n][r] + bv[n];
        }
    }
}

// ---------------------------------------------------------------------------
extern "C" void kernel_launch(void* const* d_in, const int* in_sizes, int n_in,
                              void* d_out, int out_size, void* d_ws, size_t ws_size,
                              hipStream_t stream) {
    const float* x     = (const float*)d_in[0];
    const float* w     = (const float*)d_in[1];
    const float* bias  = (const float*)d_in[2];
    const float* coeff = (const float*)d_in[3];
    const int*   msz   = (const int*)d_in[4];
    float* out = (float*)d_out;

    unsigned short* xb = (unsigned short*)d_ws;                    // 32 MB
    unsigned short* wb = xb + (size_t)N_ROWS * I_DIM;              // 32 MB

    // cvt part: 4096 blocks; synth part: 512 blocks
    prep<<<4096 + 512, 256, 0, stream>>>(x, xb, w, coeff, wb);

    gemm_moe<<<B_SEG * (1024 / BM) * (1024 / BN), 512, 0, stream>>>(xb, wb, bias, msz, out);
}

// Round 3
// 192.913 us; speedup vs baseline: 1.0214x; 1.0214x over previous
//
#include <hip/hip_runtime.h>
#include <hip/hip_bf16.h>
#include <stdint.h>

// Problem constants (fixed by reference setup_inputs)
constexpr int E_NUM  = 8;
constexpr int I_DIM  = 1024;
constexpr int O_DIM  = 1024;
constexpr int B_SEG  = 16;
constexpr int N_ROWS = 16384;

// GEMM tiling: 256x256 tile, BK=64, 512 threads = 8 waves (2 M x 4 N)
constexpr int BM = 256, BN = 256, BK = 64;
constexpr int NT = I_DIM / BK;          // 16 K-tiles

typedef __bf16 bf16x8 __attribute__((ext_vector_type(8)));
typedef float  f32x4  __attribute__((ext_vector_type(4)));
typedef unsigned short ushortx8 __attribute__((ext_vector_type(8)));

#define AS1 __attribute__((address_space(1)))
#define AS3 __attribute__((address_space(3)))

__device__ __forceinline__ unsigned short f2bf(float f) {
    unsigned int u = __float_as_uint(f);
    u += 0x7fffu + ((u >> 16) & 1u);
    return (unsigned short)(u >> 16);
}

// ---------------------------------------------------------------------------
// prep: fused synth_w (blocks 0..1023 -- FIRST, long-running) + cvt_x
// (blocks 1024..5119). Synth blocks start immediately and overlap cvt.
// Synth split 2x by segment-group to halve its serial chain.
// ---------------------------------------------------------------------------
__global__ __launch_bounds__(256) void prep(const float* __restrict__ x,
                                            unsigned short* __restrict__ xb,
                                            const float* __restrict__ w,
                                            const float* __restrict__ coeff,
                                            unsigned short* __restrict__ wb) {
    __shared__ float sc[B_SEG * E_NUM];
    const int bid = blockIdx.x;
    const int tid = threadIdx.x;

    if (bid < 1024) {
        // ---- synth part: W_b[o,i] = sum_e coeff[b,e] * weights[e,o,i] ----
        if (tid < B_SEG * E_NUM) sc[tid] = coeff[tid];
        __syncthreads();

        const int sb = (bid & 1) * 8;                          // segment group
        size_t idx = ((size_t)(bid >> 1) * 256 + tid) * 8;     // into [O*I)
        float4 wv0[E_NUM], wv1[E_NUM];
#pragma unroll
        for (int e = 0; e < E_NUM; e++) {
            const float4* p = (const float4*)(w + (size_t)e * O_DIM * I_DIM + idx);
            wv0[e] = p[0];
            wv1[e] = p[1];
        }

#pragma unroll
        for (int bq = 0; bq < 8; bq++) {
            const int b = sb + bq;
            float a[8] = {0,0,0,0,0,0,0,0};
#pragma unroll
            for (int e = 0; e < E_NUM; e++) {
                float c = sc[b * E_NUM + e];
                a[0] += c * wv0[e].x; a[1] += c * wv0[e].y;
                a[2] += c * wv0[e].z; a[3] += c * wv0[e].w;
                a[4] += c * wv1[e].x; a[5] += c * wv1[e].y;
                a[6] += c * wv1[e].z; a[7] += c * wv1[e].w;
            }
            ushortx8 o;
#pragma unroll
            for (int j = 0; j < 8; j++) o[j] = f2bf(a[j]);
            *(ushortx8*)(wb + (size_t)b * O_DIM * I_DIM + idx) = o;
        }
    } else {
        // ---- cvt part: x fp32 -> bf16, 64B in / 32B out per thread ----
        size_t idx = ((size_t)(bid - 1024) * 256 + tid) * 16;
        const float4* p = (const float4*)(x + idx);
        float4 v0 = p[0], v1 = p[1], v2 = p[2], v3 = p[3];
        ushortx8 o0, o1;
        o0[0] = f2bf(v0.x); o0[1] = f2bf(v0.y); o0[2] = f2bf(v0.z); o0[3] = f2bf(v0.w);
        o0[4] = f2bf(v1.x); o0[5] = f2bf(v1.y); o0[6] = f2bf(v1.z); o0[7] = f2bf(v1.w);
        o1[0] = f2bf(v2.x); o1[1] = f2bf(v2.y); o1[2] = f2bf(v2.z); o1[3] = f2bf(v2.w);
        o1[4] = f2bf(v3.x); o1[5] = f2bf(v3.y); o1[6] = f2bf(v3.z); o1[7] = f2bf(v3.w);
        *(ushortx8*)(xb + idx)     = o0;
        *(ushortx8*)(xb + idx + 8) = o1;
    }
}

// ---------------------------------------------------------------------------
// opaque LDS read (rule 18: manual lgkmcnt + sched_barrier afterwards)
// ---------------------------------------------------------------------------
__device__ __forceinline__ bf16x8 lds_read_b128(unsigned addr) {
    bf16x8 r;
    asm volatile("ds_read_b128 %0, %1" : "=v"(r) : "v"(addr));
    return r;
}

// ---------------------------------------------------------------------------
// Kernel 3: per-segment GEMM, C = X * W_seg^T + bias.
// 256x256 tile, BK=64, 8 waves (2Mx4N, stripe-interleaved). Full-tile
// double buffer (even tiles in slots {0,1}, odd in {2,3}) staged at
// HALF-TILE granularity, one half per phase, into the opposite buffer.
// Staggered consumption: ph0 (mh0,nh0) ph1 (mh1,nh0) ph2 (mh1,nh1)
// ph3 (mh0,nh1 -- A-h0 reused from regs, no ds_reads). Counted vmcnt(4)
// at ends of ph0/ph1/ph3 retires loads issued >=2 phases earlier; >=4
// loads always in flight. 24 ds_read_b128 per wave per K-tile.
// ---------------------------------------------------------------------------
__global__ __launch_bounds__(512, 2) void gemm_moe(
    const unsigned short* __restrict__ xb,   // [N][I] bf16 bits
    const unsigned short* __restrict__ wb,   // [B][O][I] bf16 bits
    const float* __restrict__ bias,          // [O]
    const int* __restrict__ msz,             // [B]
    float* __restrict__ out)                 // [N][O] fp32
{
    __shared__ __align__(16) char sLDS[131072];   // A: 4x16KB, B: 4x16KB

    // ---- XCD-aware mapping: 256 blocks, lid%8 = XCD, 2 segments per XCD,
    // 4x4 tiles of 256^2 per segment.
    const int lid  = blockIdx.x;            // 0..255
    const int xcd  = lid & 7;
    const int idx  = lid >> 3;              // 0..31
    const int seg  = (xcd << 1) | (idx >> 4);
    const int t16  = idx & 15;
    const int mblk = t16 >> 2;
    const int nblk = t16 & 3;

    int off = 0;
    for (int b = 0; b < seg; b++) off += msz[b];
    const int row0 = off + mblk * BM;
    const int col0 = nblk * BN;
    const unsigned short* wseg = wb + (size_t)seg * O_DIM * I_DIM;

    const int tid  = threadIdx.x;
    const int wave = tid >> 6;              // 0..7
    const int lane = tid & 63;
    const int wr = wave >> 2, wc = wave & 3;
    const int quad = lane >> 4, l16 = lane & 15;

    // ---- staging source geometry: 512 threads cover one 128x64 half-tile
    // with 2 global_load_lds (64 rows each). LDS dest linear; K-chunk XOR
    // swizzle (chunk ^= row&7) applied to the per-lane GLOBAL source.
    const int srow8  = lane >> 3;                       // 0..7
    const int schunk = (lane & 7) ^ srow8;              // swizzled K-chunk
    const unsigned short* gA0 = xb   + (size_t)(row0 + wave * 8 + srow8) * I_DIM + schunk * 8;
    const unsigned short* gA1 = gA0 + (size_t)128 * I_DIM;
    const unsigned short* gB0 = wseg + (size_t)(col0 + wave * 8 + srow8) * I_DIM + schunk * 8;
    const unsigned short* gB1 = gB0 + (size_t)128 * I_DIM;

    // ---- ds_read lane addresses (bytes). Row within half: A: mm*32 +
    // wr*16 + l16 ; B: nn*64 + wc*16 + l16. chunk = (kk*4+quad)^(l16&7).
    const unsigned rdA0 = (unsigned)((wr * 16 + l16) * 128 + (((0 + quad) ^ (l16 & 7)) * 16));
    const unsigned rdA1 = (unsigned)((wr * 16 + l16) * 128 + (((4 + quad) ^ (l16 & 7)) * 16));
    const unsigned rdB0 = (unsigned)(65536 + (wc * 16 + l16) * 128 + (((0 + quad) ^ (l16 & 7)) * 16));
    const unsigned rdB1 = (unsigned)(65536 + (wc * 16 + l16) * 128 + (((4 + quad) ^ (l16 & 7)) * 16));

    bf16x8 af0[4][2], af1[4][2], b0[2][2], b1[2][2];
    f32x4 acc[8][4];
#pragma unroll
    for (int m = 0; m < 8; ++m)
#pragma unroll
        for (int n = 0; n < 4; ++n)
            acc[m][n] = (f32x4){0.f, 0.f, 0.f, 0.f};

#define LOAD_A(DST, S) do { _Pragma("unroll") for (int mm = 0; mm < 4; ++mm) {      \
        DST[mm][0] = lds_read_b128(rdA0 + (S) * 16384u + mm * 4096u);               \
        DST[mm][1] = lds_read_b128(rdA1 + (S) * 16384u + mm * 4096u); } } while (0)
#define LOAD_B(DST, S) do { _Pragma("unroll") for (int nn = 0; nn < 2; ++nn) {      \
        DST[nn][0] = lds_read_b128(rdB0 + (S) * 16384u + nn * 8192u);               \
        DST[nn][1] = lds_read_b128(rdB1 + (S) * 16384u + nn * 8192u); } } while (0)

#define STAGE_A(H, S, ST) do {                                                      \
        const unsigned short* g_ = ((H) ? gA1 : gA0) + (size_t)(ST) * 64;           \
        __builtin_amdgcn_global_load_lds((const AS1 void*)g_,                       \
            (AS3 void*)(sLDS + (S) * 16384 + wave * 1024), 16, 0, 0);               \
        __builtin_amdgcn_global_load_lds((const AS1 void*)(g_ + (size_t)64 * I_DIM),\
            (AS3 void*)(sLDS + (S) * 16384 + 8192 + wave * 1024), 16, 0, 0); } while (0)
#define STAGE_B(H, S, ST) do {                                                      \
        const unsigned short* g_ = ((H) ? gB1 : gB0) + (size_t)(ST) * 64;           \
        __builtin_amdgcn_global_load_lds((const AS1 void*)g_,                       \
            (AS3 void*)(sLDS + 65536 + (S) * 16384 + wave * 1024), 16, 0, 0);       \
        __builtin_amdgcn_global_load_lds((const AS1 void*)(g_ + (size_t)64 * I_DIM),\
            (AS3 void*)(sLDS + 65536 + (S) * 16384 + 8192 + wave * 1024), 16, 0, 0); } while (0)

#define MFMA_Q(MH, NH, A, BV) do { _Pragma("unroll") for (int mm = 0; mm < 4; ++mm) \
        _Pragma("unroll") for (int nn = 0; nn < 2; ++nn)                            \
        _Pragma("unroll") for (int kk = 0; kk < 2; ++kk)                            \
            acc[(MH) * 4 + mm][(NH) * 2 + nn] =                                     \
                __builtin_amdgcn_mfma_f32_16x16x32_bf16(A[mm][kk], BV[nn][kk],      \
                    acc[(MH) * 4 + mm][(NH) * 2 + nn], 0, 0, 0); } while (0)

#define PH_MID() do { __builtin_amdgcn_sched_barrier(0);                            \
        __builtin_amdgcn_s_barrier();                                               \
        asm volatile("s_waitcnt lgkmcnt(0)");                                       \
        __builtin_amdgcn_sched_barrier(0);                                          \
        __builtin_amdgcn_s_setprio(1); } while (0)
#define PH_END_W() do { __builtin_amdgcn_s_setprio(0);                              \
        __builtin_amdgcn_sched_barrier(0);                                          \
        asm volatile("s_waitcnt vmcnt(4)");                                         \
        __builtin_amdgcn_sched_barrier(0);                                          \
        __builtin_amdgcn_s_barrier(); } while (0)
#define PH_END_N() do { __builtin_amdgcn_s_setprio(0);                              \
        __builtin_amdgcn_sched_barrier(0);                                          \
        __builtin_amdgcn_s_barrier(); } while (0)

    // TILE: read A/B halves from slots R0 (h0), R1 (h1); stage tile t+1's
    // four halves (one per phase) into slots S0, S1. Stage targets are
    // never read this tile; their last reader finished >=2 barriers ago.
#define TILE(R0, R1, S0, S1, ST) do {                                               \
        LOAD_A(af0, R0); LOAD_B(b0, R0); STAGE_A(0, S0, ST);                        \
        PH_MID(); MFMA_Q(0, 0, af0, b0); PH_END_W();                                \
        LOAD_A(af1, R1); STAGE_B(0, S0, ST);                                        \
        PH_MID(); MFMA_Q(1, 0, af1, b0); PH_END_W();                                \
        LOAD_B(b1, R1); STAGE_A(1, S1, ST);                                         \
        PH_MID(); MFMA_Q(1, 1, af1, b1); PH_END_N();                                \
        STAGE_B(1, S1, ST);                                                         \
        PH_MID(); MFMA_Q(0, 1, af0, b1); PH_END_W();                                \
    } while (0)

    // ---- prologue: tile0's four halves into slots 0,0,1,1 in the steady-
    // state order; vmcnt(4) retires Ah0,Bh0 -- Ah1,Bh1 still in flight.
    STAGE_A(0, 0, 0); STAGE_B(0, 0, 0);
    STAGE_A(1, 1, 0); STAGE_B(1, 1, 0);
    asm volatile("s_waitcnt vmcnt(4)");
    __builtin_amdgcn_sched_barrier(0);
    __builtin_amdgcn_s_barrier();

#pragma unroll 1
    for (int tp = 0; tp < 8; ++tp) {
        const int t0 = 2 * tp, t1 = t0 + 1;
        const int st0 = (t0 + 1 < NT) ? t0 + 1 : NT - 1;   // clamped tail
        const int st1 = (t1 + 1 < NT) ? t1 + 1 : NT - 1;   // keeps credits uniform
        TILE(0, 1, 2, 3, st0);   // even tile: read slots {0,1}, stage {2,3}
        TILE(2, 3, 0, 1, st1);   // odd tile:  read slots {2,3}, stage {0,1}
    }

#undef TILE
#undef PH_END_N
#undef PH_END_W
#undef PH_MID
#undef MFMA_Q
#undef STAGE_B
#undef STAGE_A
#undef LOAD_B
#undef LOAD_A

    // ---- epilogue: C/D layout col=lane&15, row=quad*4+reg; stripe mapping:
    // row = row0 + m*32 + wr*16 + ..., col = col0 + n*64 + wc*16 + l16.
    float bv[4];
#pragma unroll
    for (int n = 0; n < 4; ++n)
        bv[n] = bias[col0 + n * 64 + wc * 16 + l16];

#pragma unroll
    for (int m = 0; m < 8; ++m) {
#pragma unroll
        for (int r = 0; r < 4; ++r) {
            int row = row0 + m * 32 + wr * 16 + quad * 4 + r;
            float* po = out + (size_t)row * O_DIM + col0 + wc * 16 + l16;
#pragma unroll
            for (int n = 0; n < 4; ++n)
                po[n * 64] = acc[m][n][r] + bv[n];
        }
    }
}

// ---------------------------------------------------------------------------
extern "C" void kernel_launch(void* const* d_in, const int* in_sizes, int n_in,
                              void* d_out, int out_size, void* d_ws, size_t ws_size,
                              hipStream_t stream) {
    const float* x     = (const float*)d_in[0];
    const float* w     = (const float*)d_in[1];
    const float* bias  = (const float*)d_in[2];
    const float* coeff = (const float*)d_in[3];
    const int*   msz   = (const int*)d_in[4];
    float* out = (float*)d_out;

    unsigned short* xb = (unsigned short*)d_ws;                    // 32 MB
    unsigned short* wb = xb + (size_t)N_ROWS * I_DIM;              // 32 MB

    // synth part: 1024 blocks (first); cvt part: 4096 blocks
    prep<<<1024 + 4096, 256, 0, stream>>>(x, xb, w, coeff, wb);

    gemm_moe<<<B_SEG * (1024 / BM) * (1024 / BN), 512, 0, stream>>>(xb, wb, bias, msz, out);
}